// Round 1
// baseline (133.325 us; speedup 1.0000x reference)
//
#include <hip/hip_runtime.h>
#include <hip/hip_bf16.h>
#include <cstdint>

#define B_    2
#define C_    256
#define H_    64
#define W_    64
#define P_    (H_*W_)      // 4096
#define N_    4
#define RAD   4
#define K2_   81
#define CTOT  (4*K2_)      // 324

typedef __bf16 bf16x8 __attribute__((ext_vector_type(8)));
typedef float  f32x4  __attribute__((ext_vector_type(4)));

__device__ __forceinline__ void gload_lds16(const void* g, void* l) {
    __builtin_amdgcn_global_load_lds(
        (const __attribute__((address_space(1))) void*)g,
        (__attribute__((address_space(3))) void*)l,
        16, 0, 0);
}

// ---------------------------------------------------------------------------
// Transpose + convert, both maps in one dispatch:
// in (B, C, P) fp32  ->  out (B, P, C) bf16
// ---------------------------------------------------------------------------
__global__ void transpose_cvt(const float* __restrict__ in0,
                              const float* __restrict__ in1,
                              __hip_bfloat16* __restrict__ out0,
                              __hip_bfloat16* __restrict__ out1) {
    __shared__ float tile[32][33];
    const int z     = blockIdx.z;
    const int which = z >> 1;
    const int b     = z & 1;
    const float* in          = which ? in1  : in0;
    __hip_bfloat16* out      = which ? out1 : out0;
    const int p0 = blockIdx.x * 32;
    const int c0 = blockIdx.y * 32;
    const int tx = threadIdx.x;   // 0..31
    const int ty = threadIdx.y;   // 0..7
    const float* src = in + ((size_t)b * C_ + c0) * P_ + p0;
    #pragma unroll
    for (int i = 0; i < 32; i += 8)
        tile[ty + i][tx] = src[(size_t)(ty + i) * P_ + tx];   // tile[c][p]
    __syncthreads();
    __hip_bfloat16* dst = out + ((size_t)b * P_ + p0) * C_ + c0;
    #pragma unroll
    for (int i = 0; i < 32; i += 8)
        dst[(size_t)(ty + i) * C_ + tx] = __float2bfloat16(tile[tx][ty + i]);
}

// ---------------------------------------------------------------------------
// Batched GEMM with fused level-1 pooling AND fused level-0 patch extraction.
// Key change vs previous version: the full 67 MB level-0 correlation volume
// is NEVER written to HBM. Each block's 128-column tile is exactly 2 image
// rows (2*bx, 2*bx+1) of every query's 64x64 map; the block extracts the
// level-0 gather patch rows that land in those 2 rows (determined by coords,
// known before the GEMM) and writes them to a compact 7.2 MB patch buffer.
// patch0 layout: (b, p, n, 110) bf16, slot kj*11+ki (stride-11 rows, same as
// the gather kernel's LDS patch layout). Unwritten slots = poison; the
// gather masks them with the identical validity predicate (select, not mul).
// ---------------------------------------------------------------------------
#define TSTR 136   // epilogue tile stride in shorts (272 B -> 16B-aligned)

__global__ __launch_bounds__(256) void gemm_corr(
    const short* __restrict__ f1t,   // (B, 4096, 256) bf16 bits
    const short* __restrict__ f2t,   // (B, 4096, 256) bf16 bits
    const float* __restrict__ coords,
    __hip_bfloat16* __restrict__ corr1,   // (B, 4096, 32, 32) bf16
    __hip_bfloat16* __restrict__ patch0)  // (B, 4096, 4, 110) bf16
{
    __shared__ short smem[128 * TSTR];   // 17408 shorts
    short* As = smem;                    // 128*64
    short* Bs = smem + 8192;             // 128*64

    const int tid  = threadIdx.x;
    const int lane = tid & 63;
    const int wv   = tid >> 6;
    const int wm   = (wv >> 1) * 64;
    const int wn   = (wv & 1) * 64;
    const int b    = blockIdx.z;
    const int bx   = blockIdx.x;
    const int m0   = blockIdx.y * 128;
    const int n0   = bx * 128;
    const int qd   = lane >> 4;
    const int l15  = lane & 15;

    const short* gA[4];
    const short* gB[4];
    int ldsOff[4];
    #pragma unroll
    for (int it = 0; it < 4; ++it) {
        const int ci = it * 256 + tid;
        const int r  = ci >> 3;
        const int cp = ci & 7;
        const int kc = cp ^ (r & 7);
        gA[it] = f1t + ((size_t)(b * P_ + m0 + r)) * C_ + kc * 8;
        gB[it] = f2t + ((size_t)(b * P_ + n0 + r)) * C_ + kc * 8;
        ldsOff[it] = (it * 256 + wv * 64) * 8;
    }

    int aAddr[4][2], bAddr[4][2];
    #pragma unroll
    for (int i = 0; i < 4; ++i) {
        const int m = wm + i * 16 + l15;
        const int n = wn + i * 16 + l15;
        #pragma unroll
        for (int s = 0; s < 2; ++s) {
            const int lc = s * 4 + qd;
            aAddr[i][s] = m * 64 + ((lc ^ (m & 7)) * 8);
            bAddr[i][s] = n * 64 + ((lc ^ (n & 7)) * 8);
        }
    }

    f32x4 zero = {0.f, 0.f, 0.f, 0.f};
    f32x4 acc[4][4];
    #pragma unroll
    for (int mi = 0; mi < 4; ++mi)
        #pragma unroll
        for (int ni = 0; ni < 4; ++ni)
            acc[mi][ni] = zero;

    for (int kt = 0; kt < 4; ++kt) {
        const int k0 = kt * 64;
        #pragma unroll
        for (int it = 0; it < 4; ++it) {
            gload_lds16(gA[it] + k0, As + ldsOff[it]);
            gload_lds16(gB[it] + k0, Bs + ldsOff[it]);
        }
        __syncthreads();
        #pragma unroll
        for (int s = 0; s < 2; ++s) {
            bf16x8 af[4], bfr[4];
            #pragma unroll
            for (int i = 0; i < 4; ++i) {
                af[i]  = *(const bf16x8*)(As + aAddr[i][s]);
                bfr[i] = *(const bf16x8*)(Bs + bAddr[i][s]);
            }
            #pragma unroll
            for (int mi = 0; mi < 4; ++mi)
                #pragma unroll
                for (int ni = 0; ni < 4; ++ni)
                    acc[mi][ni] = __builtin_amdgcn_mfma_f32_16x16x32_bf16(
                        af[mi], bfr[ni], acc[mi][ni], 0, 0, 0);
        }
        __syncthreads();
    }

    const float sc = 0.0625f;   // 1/sqrt(256)
    __hip_bfloat16* tile = (__hip_bfloat16*)smem;
    #pragma unroll
    for (int mi = 0; mi < 4; ++mi) {
        #pragma unroll
        for (int ni = 0; ni < 4; ++ni) {
            #pragma unroll
            for (int r = 0; r < 4; ++r) {
                const int rl = wm + mi * 16 + qd * 4 + r;
                const int cl = wn + ni * 16 + l15;
                tile[rl * TSTR + cl] = __float2bfloat16(acc[mi][ni][r] * sc);
            }
        }
    }
    __syncthreads();

    // ---- fused level-1 pooling (2x2 avg of this block's 2 image rows) ----
    #pragma unroll
    for (int i = 0; i < 16; ++i) {
        const int oid = i * 256 + tid;
        const int pr  = oid >> 5;
        const int pc  = oid & 31;
        const uint32_t u0 = *(const uint32_t*)(smem + pr * TSTR + 2 * pc);
        const uint32_t u1 = *(const uint32_t*)(smem + pr * TSTR + 64 + 2 * pc);
        const float a0 = __uint_as_float(u0 << 16);
        const float a1 = __uint_as_float(u0 & 0xffff0000u);
        const float b0 = __uint_as_float(u1 << 16);
        const float b1 = __uint_as_float(u1 & 0xffff0000u);
        corr1[((size_t)(b * P_ + m0 + pr)) * 1024 + bx * 32 + pc] =
            __float2bfloat16((a0 + a1 + b0 + b1) * 0.25f);
    }

    // ---- fused level-0 patch extraction ----
    // This block holds image rows {2*bx, 2*bx+1} for queries p = m0..m0+127.
    // For each (p, n): if patch row kj = gr - y0 lands in [0,10), copy the
    // in-range columns to patch0[(b,p,n)][kj*11+ki]. Exactly one block
    // writes any given patch row -> race-free. Out-of-range slots stay
    // unwritten (reader masks with the identical predicate).
    const int row0 = 2 * bx;
    #pragma unroll
    for (int pair0 = 0; pair0 < 2; ++pair0) {
        const int pair = pair0 * 256 + tid;   // 0..511
        const int n    = pair & 3;
        const int pi   = pair >> 2;           // 0..127
        const int p    = m0 + pi;
        const float cx = coords[((size_t)((b * N_ + n) * 2 + 0)) * P_ + p];
        const float cy = coords[((size_t)((b * N_ + n) * 2 + 1)) * P_ + p];
        const int x0 = (int)floorf(cx) - RAD;
        const int y0 = (int)floorf(cy) - RAD;
        __hip_bfloat16* pd = patch0 + ((size_t)(b * P_ + p) * N_ + n) * 110;
        #pragma unroll
        for (int rr = 0; rr < 2; ++rr) {
            const int kj = (row0 + rr) - y0;
            if ((unsigned)kj < 10u) {
                const __hip_bfloat16* ts = tile + pi * TSTR + rr * 64;
                #pragma unroll
                for (int ki = 0; ki < 10; ++ki) {
                    const int gc = x0 + ki;
                    if ((unsigned)gc < 64u)
                        pd[kj * 11 + ki] = ts[gc];
                }
            }
        }
    }
}

// ---------------------------------------------------------------------------
// Gather v6: one block per (b,p), one wave per n.
// Level-0 patch now comes from the compact patch0 buffer (220 B contiguous
// per (p,n), coalesced) instead of scattered reads into a 67 MB volume.
// Level-1 patch from c1 (which Phase A reads in full anyway -> L1/L2 hit).
// ---------------------------------------------------------------------------
__global__ __launch_bounds__(256) void gather6(
    const float* __restrict__ coords,
    const __hip_bfloat16* __restrict__ patch0g,
    const __hip_bfloat16* __restrict__ c1,
    float* __restrict__ out) {
    __shared__ float pool_sm[320];     // [0..255]=c2 (16x16), [256..319]=c3 (8x8)
    __shared__ float patch[4][440];    // per wave: 4 levels x 110

    const int tid  = threadIdx.x;
    const int lane = tid & 63;
    const int n    = tid >> 6;
    const int bp   = blockIdx.x;       // 0..8191
    const int b    = bp >> 12;
    const int p    = bp & (P_ - 1);

    const __hip_bfloat16* c1b = c1 + (size_t)bp * 1024;

    // ---- geometry, all 4 levels, all lanes ----
    const float cx = coords[((size_t)((b * N_ + n) * 2 + 0)) * P_ + p];
    const float cy = coords[((size_t)((b * N_ + n) * 2 + 1)) * P_ + p];
    int x0i[4], y0i[4];
    float w00[4], w01[4], w10[4], w11[4];
    #pragma unroll
    for (int l = 0; l < 4; ++l) {
        const float inv = (l == 0) ? 1.f : (l == 1) ? 0.5f : (l == 2) ? 0.25f : 0.125f;
        const float x = cx * inv, y = cy * inv;
        const float x0f = floorf(x), y0f = floorf(y);
        const float wx = x - x0f, wy = y - y0f;
        x0i[l] = (int)x0f - RAD;
        y0i[l] = (int)y0f - RAD;
        w00[l] = (1.f - wy) * (1.f - wx);
        w01[l] = (1.f - wy) * wx;
        w10[l] = wy * (1.f - wx);
        w11[l] = wy * wx;
    }

    // ---- prefetch level-0 (compact patch buffer) + level-1 (c1) ----
    float pv[2][2];
    {
        const __hip_bfloat16* p0 = patch0g + ((size_t)bp * N_ + n) * 110;
        #pragma unroll
        for (int it = 0; it < 2; ++it) {
            const int idx = it * 64 + lane;
            const int r   = idx / 11;
            const int cc  = idx - r * 11;
            const int gr  = y0i[0] + r, gc = x0i[0] + cc;
            float v = 0.f;
            if ((idx < 110) & (cc < 10) & ((unsigned)gr < 64u) &
                ((unsigned)gc < 64u))
                v = __bfloat162float(p0[idx]);
            pv[0][it] = v;
        }
    }
    #pragma unroll
    for (int it = 0; it < 2; ++it) {
        const int idx = it * 64 + lane;
        const int r   = idx / 11;
        const int cc  = idx - r * 11;
        const int gr  = y0i[1] + r, gc = x0i[1] + cc;
        float v = 0.f;
        if ((idx < 110) & (cc < 10) & ((unsigned)gr < 32u) &
            ((unsigned)gc < 32u))
            v = __bfloat162float(c1b[(gr << 5) + gc]);
        pv[1][it] = v;
    }

    // ---- Phase A: pool c1 -> c2, c3 (LDS); overlaps prefetch latency ----
    {
        const int y2 = tid >> 4, x2 = tid & 15;
        const uint32_t u0 = *(const uint32_t*)(c1b + (2 * y2) * 32 + 2 * x2);
        const uint32_t u1 = *(const uint32_t*)(c1b + (2 * y2 + 1) * 32 + 2 * x2);
        const float a0 = __uint_as_float(u0 << 16);
        const float a1 = __uint_as_float(u0 & 0xffff0000u);
        const float b0 = __uint_as_float(u1 << 16);
        const float b1 = __uint_as_float(u1 & 0xffff0000u);
        pool_sm[tid] = (a0 + a1 + b0 + b1) * 0.25f;
    }
    __syncthreads();
    if (tid < 64) {
        const int y3 = tid >> 3, x3 = tid & 7;
        const float* r0 = pool_sm + (2 * y3) * 16 + 2 * x3;
        pool_sm[256 + tid] = (r0[0] + r0[1] + r0[16] + r0[17]) * 0.25f;
    }
    __syncthreads();

    // ---- patch fill: lvl0/1 from regs, lvl2/3 from pool_sm ----
    float* pw = patch[n];
    #pragma unroll
    for (int lvl = 0; lvl < 2; ++lvl) {
        #pragma unroll
        for (int it = 0; it < 2; ++it) {
            const int idx = it * 64 + lane;
            if (idx < 110) pw[lvl * 110 + idx] = pv[lvl][it];
        }
    }
    #pragma unroll
    for (int lvl = 2; lvl < 4; ++lvl) {
        const int hw   = (lvl == 2) ? 16 : 8;
        const int sh   = (lvl == 2) ? 4 : 3;
        const int base = (lvl == 2) ? 0 : 256;
        #pragma unroll
        for (int it = 0; it < 2; ++it) {
            const int idx = it * 64 + lane;
            if (idx < 110) {
                const int r  = idx / 11;
                const int cc = idx - r * 11;
                const int gr = y0i[lvl] + r, gc = x0i[lvl] + cc;
                float v = 0.f;
                if ((cc < 10) & ((unsigned)gr < (unsigned)hw) &
                    ((unsigned)gc < (unsigned)hw))
                    v = pool_sm[base + (gr << sh) + gc];
                pw[lvl * 110 + idx] = v;
            }
        }
    }
    // no barrier: patch[n] is wave-private, wave LDS ops are in-order

    // ---- Phase C: per-level unrolled, 81 outputs each ----
    const size_t obase = ((size_t)(b * N_ + n) * P_ + p) * CTOT;
    #pragma unroll
    for (int lvl = 0; lvl < 4; ++lvl) {
        const float* pl = pw + lvl * 110;
        float* ol = out + obase + lvl * K2_;
        #pragma unroll
        for (int it = 0; it < 2; ++it) {
            const int k2 = it * 64 + lane;
            if (k2 < K2_) {
                const int ki = k2 / 9;        // added to x -> patch col
                const int kj = k2 - ki * 9;   // added to y -> patch row
                const float* pr = pl + kj * 11 + ki;
                ol[k2] = w00[lvl] * pr[0] + w01[lvl] * pr[1] +
                         w10[lvl] * pr[11] + w11[lvl] * pr[12];
            }
        }
    }
}

// ---------------------------------------------------------------------------
extern "C" void kernel_launch(void* const* d_in, const int* in_sizes, int n_in,
                              void* d_out, int out_size, void* d_ws, size_t ws_size,
                              hipStream_t stream) {
    const float* fmap1  = (const float*)d_in[0];
    const float* fmap2  = (const float*)d_in[1];
    const float* coords = (const float*)d_in[2];
    float* out = (float*)d_out;

    char* ws = (char*)d_ws;
    __hip_bfloat16* f1t    = (__hip_bfloat16*)ws;                 //  4,194,304 B
    __hip_bfloat16* f2t    = (__hip_bfloat16*)(ws + 4194304);     //  4,194,304 B
    __hip_bfloat16* c1     = (__hip_bfloat16*)(ws + 8388608);     // 16,777,216 B
    __hip_bfloat16* patch0 = (__hip_bfloat16*)(ws + 25165824);    //  7,208,960 B

    // 1) transpose+convert both fmaps (one dispatch)
    {
        dim3 grid(P_ / 32, C_ / 32, 2 * B_);
        dim3 blk(32, 8);
        transpose_cvt<<<grid, blk, 0, stream>>>(fmap1, fmap2, f1t, f2t);
    }

    // 2) all-pairs correlation + fused level-1 pooling + fused lvl0 patch
    {
        dim3 grid(P_ / 128, P_ / 128, B_);
        gemm_corr<<<grid, 256, 0, stream>>>((const short*)f1t, (const short*)f2t,
                                            coords, c1, patch0);
    }

    // 3) fused pool2+pool3 + 4-level bilinear gather
    gather6<<<B_ * P_, 256, 0, stream>>>(coords, patch0, c1, out);
}

// Round 2
// 120.919 us; speedup vs baseline: 1.1026x; 1.1026x over previous
//
#include <hip/hip_runtime.h>
#include <hip/hip_bf16.h>
#include <cstdint>

#define B_    2
#define C_    256
#define H_    64
#define W_    64
#define P_    (H_*W_)      // 4096
#define N_    4
#define RAD   4
#define K2_   81
#define CTOT  (4*K2_)      // 324

typedef __bf16 bf16x8 __attribute__((ext_vector_type(8)));
typedef float  f32x4  __attribute__((ext_vector_type(4)));

__device__ __forceinline__ void gload_lds16(const void* g, void* l) {
    __builtin_amdgcn_global_load_lds(
        (const __attribute__((address_space(1))) void*)g,
        (__attribute__((address_space(3))) void*)l,
        16, 0, 0);
}

// ---------------------------------------------------------------------------
// Transpose + convert, both maps in one dispatch:
// in (B, C, P) fp32  ->  out (B, P, C) bf16
// ---------------------------------------------------------------------------
__global__ void transpose_cvt(const float* __restrict__ in0,
                              const float* __restrict__ in1,
                              __hip_bfloat16* __restrict__ out0,
                              __hip_bfloat16* __restrict__ out1) {
    __shared__ float tile[32][33];
    const int z     = blockIdx.z;
    const int which = z >> 1;
    const int b     = z & 1;
    const float* in          = which ? in1  : in0;
    __hip_bfloat16* out      = which ? out1 : out0;
    const int p0 = blockIdx.x * 32;
    const int c0 = blockIdx.y * 32;
    const int tx = threadIdx.x;   // 0..31
    const int ty = threadIdx.y;   // 0..7
    const float* src = in + ((size_t)b * C_ + c0) * P_ + p0;
    #pragma unroll
    for (int i = 0; i < 32; i += 8)
        tile[ty + i][tx] = src[(size_t)(ty + i) * P_ + tx];   // tile[c][p]
    __syncthreads();
    __hip_bfloat16* dst = out + ((size_t)b * P_ + p0) * C_ + c0;
    #pragma unroll
    for (int i = 0; i < 32; i += 8)
        dst[(size_t)(ty + i) * C_ + tx] = __float2bfloat16(tile[tx][ty + i]);
}

// ---------------------------------------------------------------------------
// Batched GEMM with fused level-1 pooling AND fused level-0 patch extraction.
// The 67 MB level-0 correlation volume is never written to HBM. Each block's
// 128-column tile is exactly 2 image rows (2*bx, 2*bx+1) of every query's
// 64x64 map; the block extracts the level-0 patch rows that land in those 2
// rows and writes them compactly.
//
// patch0 layout: (b, p, n, 120) bf16 — 10 rows x stride 12 (24 B, 8B-aligned)
// so each row is written as 2x dwordx2 + 1x dword (3 wide stores, no inner
// branches). Out-of-range columns carry clamped garbage; the reader re-masks
// with its own coords-derived predicate, so garbage/poison never leaks.
// __launch_bounds__(256,3) pins VGPR <= 168 to hold the 3-blocks/CU overlap
// regime the main loop depends on (R1 regression suspect: epilogue pressure).
// ---------------------------------------------------------------------------
#define TSTR 136   // epilogue tile stride in shorts (272 B -> 16B-aligned)

__global__ __launch_bounds__(256, 3) void gemm_corr(
    const short* __restrict__ f1t,   // (B, 4096, 256) bf16 bits
    const short* __restrict__ f2t,   // (B, 4096, 256) bf16 bits
    const float* __restrict__ coords,
    __hip_bfloat16* __restrict__ corr1,   // (B, 4096, 32, 32) bf16
    __hip_bfloat16* __restrict__ patch0)  // (B, 4096, 4, 120) bf16
{
    __shared__ short smem[128 * TSTR];   // 17408 shorts
    short* As = smem;                    // 128*64
    short* Bs = smem + 8192;             // 128*64

    const int tid  = threadIdx.x;
    const int lane = tid & 63;
    const int wv   = tid >> 6;
    const int wm   = (wv >> 1) * 64;
    const int wn   = (wv & 1) * 64;
    const int b    = blockIdx.z;
    const int bx   = blockIdx.x;
    const int m0   = blockIdx.y * 128;
    const int n0   = bx * 128;
    const int qd   = lane >> 4;
    const int l15  = lane & 15;

    const short* gA[4];
    const short* gB[4];
    int ldsOff[4];
    #pragma unroll
    for (int it = 0; it < 4; ++it) {
        const int ci = it * 256 + tid;
        const int r  = ci >> 3;
        const int cp = ci & 7;
        const int kc = cp ^ (r & 7);
        gA[it] = f1t + ((size_t)(b * P_ + m0 + r)) * C_ + kc * 8;
        gB[it] = f2t + ((size_t)(b * P_ + n0 + r)) * C_ + kc * 8;
        ldsOff[it] = (it * 256 + wv * 64) * 8;
    }

    int aAddr[4][2], bAddr[4][2];
    #pragma unroll
    for (int i = 0; i < 4; ++i) {
        const int m = wm + i * 16 + l15;
        const int n = wn + i * 16 + l15;
        #pragma unroll
        for (int s = 0; s < 2; ++s) {
            const int lc = s * 4 + qd;
            aAddr[i][s] = m * 64 + ((lc ^ (m & 7)) * 8);
            bAddr[i][s] = n * 64 + ((lc ^ (n & 7)) * 8);
        }
    }

    f32x4 zero = {0.f, 0.f, 0.f, 0.f};
    f32x4 acc[4][4];
    #pragma unroll
    for (int mi = 0; mi < 4; ++mi)
        #pragma unroll
        for (int ni = 0; ni < 4; ++ni)
            acc[mi][ni] = zero;

    for (int kt = 0; kt < 4; ++kt) {
        const int k0 = kt * 64;
        #pragma unroll
        for (int it = 0; it < 4; ++it) {
            gload_lds16(gA[it] + k0, As + ldsOff[it]);
            gload_lds16(gB[it] + k0, Bs + ldsOff[it]);
        }
        __syncthreads();
        #pragma unroll
        for (int s = 0; s < 2; ++s) {
            bf16x8 af[4], bfr[4];
            #pragma unroll
            for (int i = 0; i < 4; ++i) {
                af[i]  = *(const bf16x8*)(As + aAddr[i][s]);
                bfr[i] = *(const bf16x8*)(Bs + bAddr[i][s]);
            }
            #pragma unroll
            for (int mi = 0; mi < 4; ++mi)
                #pragma unroll
                for (int ni = 0; ni < 4; ++ni)
                    acc[mi][ni] = __builtin_amdgcn_mfma_f32_16x16x32_bf16(
                        af[mi], bfr[ni], acc[mi][ni], 0, 0, 0);
        }
        __syncthreads();
    }

    const float sc = 0.0625f;   // 1/sqrt(256)
    __hip_bfloat16* tile = (__hip_bfloat16*)smem;
    #pragma unroll
    for (int mi = 0; mi < 4; ++mi) {
        #pragma unroll
        for (int ni = 0; ni < 4; ++ni) {
            #pragma unroll
            for (int r = 0; r < 4; ++r) {
                const int rl = wm + mi * 16 + qd * 4 + r;
                const int cl = wn + ni * 16 + l15;
                tile[rl * TSTR + cl] = __float2bfloat16(acc[mi][ni][r] * sc);
            }
        }
    }
    __syncthreads();

    // ---- fused level-1 pooling (2x2 avg of this block's 2 image rows) ----
    #pragma unroll
    for (int i = 0; i < 16; ++i) {
        const int oid = i * 256 + tid;
        const int pr  = oid >> 5;
        const int pc  = oid & 31;
        const uint32_t u0 = *(const uint32_t*)(smem + pr * TSTR + 2 * pc);
        const uint32_t u1 = *(const uint32_t*)(smem + pr * TSTR + 64 + 2 * pc);
        const float a0 = __uint_as_float(u0 << 16);
        const float a1 = __uint_as_float(u0 & 0xffff0000u);
        const float b0 = __uint_as_float(u1 << 16);
        const float b1 = __uint_as_float(u1 & 0xffff0000u);
        corr1[((size_t)(b * P_ + m0 + pr)) * 1024 + bx * 32 + pc] =
            __float2bfloat16((a0 + a1 + b0 + b1) * 0.25f);
    }

    // ---- fused level-0 patch extraction (wide-store version) ----
    // One thread per (p,n) pair, 2 iterations. Active-row predicate only;
    // the 10 columns are packed into 5 dwords (clamped LDS reads, garbage
    // where out-of-range — reader re-masks) and stored with 3 wide stores.
    const int row0 = 2 * bx;
    #pragma unroll 1
    for (int pair0 = 0; pair0 < 2; ++pair0) {
        const int pair = pair0 * 256 + tid;   // 0..511
        const int n    = pair & 3;
        const int pi   = pair >> 2;           // 0..127
        const int p    = m0 + pi;
        const float cx = coords[((size_t)((b * N_ + n) * 2 + 0)) * P_ + p];
        const float cy = coords[((size_t)((b * N_ + n) * 2 + 1)) * P_ + p];
        const int x0 = (int)floorf(cx) - RAD;
        const int y0 = (int)floorf(cy) - RAD;
        __hip_bfloat16* pd = patch0 + ((size_t)(b * P_ + p) * N_ + n) * 120;
        #pragma unroll
        for (int rr = 0; rr < 2; ++rr) {
            const int kj = (row0 + rr) - y0;
            if ((unsigned)kj < 10u) {
                const uint16_t* ts = (const uint16_t*)(tile + pi * TSTR + rr * 64);
                uint32_t d[5];
                #pragma unroll
                for (int q = 0; q < 5; ++q) {
                    int g0 = x0 + 2 * q;
                    int g1 = g0 + 1;
                    g0 = min(max(g0, 0), 63);
                    g1 = min(max(g1, 0), 63);
                    d[q] = (uint32_t)ts[g0] | ((uint32_t)ts[g1] << 16);
                }
                uint32_t* dst = (uint32_t*)(pd + kj * 12);   // 8B-aligned
                *(uint2*)(dst)     = make_uint2(d[0], d[1]);
                *(uint2*)(dst + 2) = make_uint2(d[2], d[3]);
                dst[4] = d[4];
            }
        }
    }
}

// ---------------------------------------------------------------------------
// Gather v7: one block per (b,p), one wave per n.
// Level-0 patch from the compact stride-12 patch0 buffer (240 B contiguous
// per (p,n), coalesced). Level-1 patch from c1 (Phase A reads it fully
// anyway -> L1/L2 hit).
// ---------------------------------------------------------------------------
__global__ __launch_bounds__(256) void gather7(
    const float* __restrict__ coords,
    const __hip_bfloat16* __restrict__ patch0g,
    const __hip_bfloat16* __restrict__ c1,
    float* __restrict__ out) {
    __shared__ float pool_sm[320];     // [0..255]=c2 (16x16), [256..319]=c3 (8x8)
    __shared__ float patch[4][440];    // per wave: 4 levels x 110

    const int tid  = threadIdx.x;
    const int lane = tid & 63;
    const int n    = tid >> 6;
    const int bp   = blockIdx.x;       // 0..8191
    const int b    = bp >> 12;
    const int p    = bp & (P_ - 1);

    const __hip_bfloat16* c1b = c1 + (size_t)bp * 1024;

    // ---- geometry, all 4 levels, all lanes ----
    const float cx = coords[((size_t)((b * N_ + n) * 2 + 0)) * P_ + p];
    const float cy = coords[((size_t)((b * N_ + n) * 2 + 1)) * P_ + p];
    int x0i[4], y0i[4];
    float w00[4], w01[4], w10[4], w11[4];
    #pragma unroll
    for (int l = 0; l < 4; ++l) {
        const float inv = (l == 0) ? 1.f : (l == 1) ? 0.5f : (l == 2) ? 0.25f : 0.125f;
        const float x = cx * inv, y = cy * inv;
        const float x0f = floorf(x), y0f = floorf(y);
        const float wx = x - x0f, wy = y - y0f;
        x0i[l] = (int)x0f - RAD;
        y0i[l] = (int)y0f - RAD;
        w00[l] = (1.f - wy) * (1.f - wx);
        w01[l] = (1.f - wy) * wx;
        w10[l] = wy * (1.f - wx);
        w11[l] = wy * wx;
    }

    // ---- prefetch level-0 (stride-12 compact patch) + level-1 (c1) ----
    // lvl0: 120 slots, row r = idx/12, col cc = idx-12r (cc<10 valid).
    float pv0[2], pv1[2];
    {
        const __hip_bfloat16* p0 = patch0g + ((size_t)bp * N_ + n) * 120;
        #pragma unroll
        for (int it = 0; it < 2; ++it) {
            const int idx = it * 64 + lane;
            const int r   = idx / 12;
            const int cc  = idx - r * 12;
            const int gr  = y0i[0] + r, gc = x0i[0] + cc;
            float v = 0.f;
            if ((idx < 120) & (cc < 10) & ((unsigned)gr < 64u) &
                ((unsigned)gc < 64u))
                v = __bfloat162float(p0[idx]);
            pv0[it] = v;
        }
    }
    #pragma unroll
    for (int it = 0; it < 2; ++it) {
        const int idx = it * 64 + lane;
        const int r   = idx / 11;
        const int cc  = idx - r * 11;
        const int gr  = y0i[1] + r, gc = x0i[1] + cc;
        float v = 0.f;
        if ((idx < 110) & (cc < 10) & ((unsigned)gr < 32u) &
            ((unsigned)gc < 32u))
            v = __bfloat162float(c1b[(gr << 5) + gc]);
        pv1[it] = v;
    }

    // ---- Phase A: pool c1 -> c2, c3 (LDS); overlaps prefetch latency ----
    {
        const int y2 = tid >> 4, x2 = tid & 15;
        const uint32_t u0 = *(const uint32_t*)(c1b + (2 * y2) * 32 + 2 * x2);
        const uint32_t u1 = *(const uint32_t*)(c1b + (2 * y2 + 1) * 32 + 2 * x2);
        const float a0 = __uint_as_float(u0 << 16);
        const float a1 = __uint_as_float(u0 & 0xffff0000u);
        const float b0 = __uint_as_float(u1 << 16);
        const float b1 = __uint_as_float(u1 & 0xffff0000u);
        pool_sm[tid] = (a0 + a1 + b0 + b1) * 0.25f;
    }
    __syncthreads();
    if (tid < 64) {
        const int y3 = tid >> 3, x3 = tid & 7;
        const float* r0 = pool_sm + (2 * y3) * 16 + 2 * x3;
        pool_sm[256 + tid] = (r0[0] + r0[1] + r0[16] + r0[17]) * 0.25f;
    }
    __syncthreads();

    // ---- patch fill: lvl0 (stride-12 -> stride-11 remap), lvl1 from regs,
    //      lvl2/3 from pool_sm ----
    float* pw = patch[n];
    #pragma unroll
    for (int it = 0; it < 2; ++it) {
        const int idx = it * 64 + lane;
        const int r   = idx / 12;
        const int cc  = idx - r * 12;
        if ((idx < 120) & (cc < 11)) pw[r * 11 + cc] = pv0[it];
    }
    #pragma unroll
    for (int it = 0; it < 2; ++it) {
        const int idx = it * 64 + lane;
        if (idx < 110) pw[110 + idx] = pv1[it];
    }
    #pragma unroll
    for (int lvl = 2; lvl < 4; ++lvl) {
        const int hw   = (lvl == 2) ? 16 : 8;
        const int sh   = (lvl == 2) ? 4 : 3;
        const int base = (lvl == 2) ? 0 : 256;
        #pragma unroll
        for (int it = 0; it < 2; ++it) {
            const int idx = it * 64 + lane;
            if (idx < 110) {
                const int r  = idx / 11;
                const int cc = idx - r * 11;
                const int gr = y0i[lvl] + r, gc = x0i[lvl] + cc;
                float v = 0.f;
                if ((cc < 10) & ((unsigned)gr < (unsigned)hw) &
                    ((unsigned)gc < (unsigned)hw))
                    v = pool_sm[base + (gr << sh) + gc];
                pw[lvl * 110 + idx] = v;
            }
        }
    }
    // no barrier: patch[n] is wave-private, wave LDS ops are in-order

    // ---- Phase C: per-level unrolled, 81 outputs each ----
    const size_t obase = ((size_t)(b * N_ + n) * P_ + p) * CTOT;
    #pragma unroll
    for (int lvl = 0; lvl < 4; ++lvl) {
        const float* pl = pw + lvl * 110;
        float* ol = out + obase + lvl * K2_;
        #pragma unroll
        for (int it = 0; it < 2; ++it) {
            const int k2 = it * 64 + lane;
            if (k2 < K2_) {
                const int ki = k2 / 9;        // added to x -> patch col
                const int kj = k2 - ki * 9;   // added to y -> patch row
                const float* pr = pl + kj * 11 + ki;
                ol[k2] = w00[lvl] * pr[0] + w01[lvl] * pr[1] +
                         w10[lvl] * pr[11] + w11[lvl] * pr[12];
            }
        }
    }
}

// ---------------------------------------------------------------------------
extern "C" void kernel_launch(void* const* d_in, const int* in_sizes, int n_in,
                              void* d_out, int out_size, void* d_ws, size_t ws_size,
                              hipStream_t stream) {
    const float* fmap1  = (const float*)d_in[0];
    const float* fmap2  = (const float*)d_in[1];
    const float* coords = (const float*)d_in[2];
    float* out = (float*)d_out;

    char* ws = (char*)d_ws;
    __hip_bfloat16* f1t    = (__hip_bfloat16*)ws;                 //  4,194,304 B
    __hip_bfloat16* f2t    = (__hip_bfloat16*)(ws + 4194304);     //  4,194,304 B
    __hip_bfloat16* c1     = (__hip_bfloat16*)(ws + 8388608);     // 16,777,216 B
    __hip_bfloat16* patch0 = (__hip_bfloat16*)(ws + 25165824);    //  7,864,320 B

    // 1) transpose+convert both fmaps (one dispatch)
    {
        dim3 grid(P_ / 32, C_ / 32, 2 * B_);
        dim3 blk(32, 8);
        transpose_cvt<<<grid, blk, 0, stream>>>(fmap1, fmap2, f1t, f2t);
    }

    // 2) all-pairs correlation + fused level-1 pooling + fused lvl0 patch
    {
        dim3 grid(P_ / 128, P_ / 128, B_);
        gemm_corr<<<grid, 256, 0, stream>>>((const short*)f1t, (const short*)f2t,
                                            coords, c1, patch0);
    }

    // 3) fused pool2+pool3 + 4-level bilinear gather
    gather7<<<B_ * P_, 256, 0, stream>>>(coords, patch0, c1, out);
}